// Round 1
// baseline (1479.601 us; speedup 1.0000x reference)
//
#include <hip/hip_runtime.h>

// GCNConv(8->64), self-loops, symmetric norm.
// out = segment_sum(dis[row]*ew*dis[col] * x[row]) @ W  + dis[i]^2 * x[i] @ W + b
// (linearity lets us aggregate in 8-dim space: 8x fewer atomics than 64-dim.)

__global__ void detect_k(const unsigned* w, unsigned* orw) {
    // If edge_index is int64 (values < 2^31), every odd 32-bit word is 0.
    __shared__ unsigned s;
    if (threadIdx.x == 0) s = 0u;
    __syncthreads();
    unsigned v = 0;
    #pragma unroll
    for (int j = 0; j < 8; ++j)
        v |= w[2 * (threadIdx.x * 8 + j) + 1];
    atomicOr(&s, v);
    __syncthreads();
    if (threadIdx.x == 0) *orw = s;   // 0 => int64 layout
}

__global__ void init_k(float* deg, float4* agg4, int N) {
    int i = blockIdx.x * blockDim.x + threadIdx.x;
    int stride = gridDim.x * blockDim.x;
    for (; i < N; i += stride) {
        deg[i] = 1.0f;                         // self-loop weight
        agg4[2 * i]     = make_float4(0.f, 0.f, 0.f, 0.f);
        agg4[2 * i + 1] = make_float4(0.f, 0.f, 0.f, 0.f);
    }
}

__global__ void deg_k(const void* ei, const float* ea, const unsigned* orw,
                      float* deg, int E) {
    const bool is64 = (*orw == 0u);
    const int* e32 = (const int*)ei;
    const long long* e64 = (const long long*)ei;
    int e = blockIdx.x * blockDim.x + threadIdx.x;
    int stride = gridDim.x * blockDim.x;
    for (; e < E; e += stride) {
        int c = is64 ? (int)e64[E + e] : e32[E + e];
        atomicAdd(&deg[c], ea[e]);
    }
}

__global__ void dis_k(float* deg, int N) {
    int i = blockIdx.x * blockDim.x + threadIdx.x;
    int stride = gridDim.x * blockDim.x;
    for (; i < N; i += stride) {
        float d = deg[i];
        deg[i] = (d > 0.f) ? rsqrtf(d) : 0.f;
    }
}

__global__ void edge_k(const void* ei, const float* ea, const unsigned* orw,
                       const float* dis, const float* x, float* agg, int E) {
    const bool is64 = (*orw == 0u);
    const int* e32 = (const int*)ei;
    const long long* e64 = (const long long*)ei;
    int e = blockIdx.x * blockDim.x + threadIdx.x;
    int stride = gridDim.x * blockDim.x;
    for (; e < E; e += stride) {
        int r, c;
        if (is64) { r = (int)e64[e]; c = (int)e64[E + e]; }
        else      { r = e32[e];      c = e32[E + e]; }
        float nrm = dis[r] * ea[e] * dis[c];
        const float4* xr = (const float4*)(x + (size_t)r * 8);
        float4 a = xr[0];
        float4 b = xr[1];
        float* ag = agg + (size_t)c * 8;
        atomicAdd(ag + 0, nrm * a.x);
        atomicAdd(ag + 1, nrm * a.y);
        atomicAdd(ag + 2, nrm * a.z);
        atomicAdd(ag + 3, nrm * a.w);
        atomicAdd(ag + 4, nrm * b.x);
        atomicAdd(ag + 5, nrm * b.y);
        atomicAdd(ag + 6, nrm * b.z);
        atomicAdd(ag + 7, nrm * b.w);
    }
}

__global__ void out_k(const float* x, const float* Wm, const float* bv,
                      const float* dis, const float* agg, float* out, int N) {
    int lane = threadIdx.x & 63;
    int wid = blockIdx.x * (blockDim.x >> 6) + (threadIdx.x >> 6);
    int nw = gridDim.x * (blockDim.x >> 6);
    float wreg[8];
    #pragma unroll
    for (int k = 0; k < 8; ++k) wreg[k] = Wm[k * 64 + lane];
    float bj = bv[lane];
    for (int i = wid; i < N; i += nw) {
        float d = dis[i];
        float ink = 0.f;
        if (lane < 8) ink = agg[i * 8 + lane] + d * d * x[i * 8 + lane];
        float acc = bj;
        #pragma unroll
        for (int k = 0; k < 8; ++k)
            acc += __shfl(ink, k) * wreg[k];
        out[(size_t)i * 64 + lane] = acc;
    }
}

extern "C" void kernel_launch(void* const* d_in, const int* in_sizes, int n_in,
                              void* d_out, int out_size, void* d_ws, size_t ws_size,
                              hipStream_t stream) {
    const float* x  = (const float*)d_in[0];
    const void*  ei = d_in[1];
    const float* ea = (const float*)d_in[2];
    const float* Wm = (const float*)d_in[3];
    const float* bv = (const float*)d_in[4];
    float* out = (float*)d_out;

    const int N = in_sizes[0] / 8;
    const int E = in_sizes[2];        // edge_attr count == E

    char* ws = (char*)d_ws;
    unsigned* orw = (unsigned*)ws;
    float* deg = (float*)(ws + 512);  // becomes dis after dis_k
    size_t agg_off = (512 + (size_t)N * 4 + 255) & ~(size_t)255;
    float* agg = (float*)(ws + agg_off);

    detect_k<<<1, 256, 0, stream>>>((const unsigned*)ei, orw);
    init_k<<<(N + 255) / 256, 256, 0, stream>>>(deg, (float4*)agg, N);
    deg_k<<<2048, 256, 0, stream>>>(ei, ea, orw, deg, E);
    dis_k<<<(N + 255) / 256, 256, 0, stream>>>(deg, N);
    edge_k<<<2048, 256, 0, stream>>>(ei, ea, orw, deg, x, agg, E);
    out_k<<<2048, 256, 0, stream>>>(x, Wm, bv, deg, agg, out, N);
}

// Round 2
// 525.137 us; speedup vs baseline: 2.8176x; 2.8176x over previous
//
#include <hip/hip_runtime.h>

// GCNConv(8->64), self-loops, symmetric norm.
// out[c] = ( dis[c] * sum_e dis[r_e]*ew_e*x[r_e]  +  dis[c]^2 * x[c] ) @ W + b
// Strategy: build CSR by destination (counting sort) -> gather-aggregate with
// zero float atomics. Atomics: 3.2M int (hist) + 3.2M int (cursor) only.

static inline size_t ws_align(size_t x) { return (x + 255) & ~(size_t)255; }

__global__ void detect_k(const unsigned* w, unsigned* orw) {
    // int64 edge_index with values < 2^31 => every odd 32-bit word is 0.
    __shared__ unsigned s;
    if (threadIdx.x == 0) s = 0u;
    __syncthreads();
    unsigned v = 0;
    #pragma unroll
    for (int j = 0; j < 8; ++j)
        v |= w[2 * (threadIdx.x * 8 + j) + 1];
    atomicOr(&s, v);
    __syncthreads();
    if (threadIdx.x == 0) *orw = s;   // 0 => int64 layout
}

__global__ void zero_k(unsigned* p, int n) {
    int i = blockIdx.x * blockDim.x + threadIdx.x;
    int st = gridDim.x * blockDim.x;
    for (; i < n; i += st) p[i] = 0u;
}

__global__ void hist_k(const void* ei, const unsigned* orw, unsigned* cnt, int E) {
    const bool is64 = (*orw == 0u);
    const int* e32 = (const int*)ei;
    const long long* e64 = (const long long*)ei;
    int e = blockIdx.x * blockDim.x + threadIdx.x;
    int st = gridDim.x * blockDim.x;
    for (; e < E; e += st) {
        int c = is64 ? (int)e64[E + e] : e32[E + e];
        atomicAdd(&cnt[c], 1u);
    }
}

// ---- exclusive scan over cnt[N] -> offs[N+1], also seeds cursor = offs ----
__global__ void s1_k(const unsigned* cnt, unsigned* bsum, int N) {
    __shared__ unsigned wsum[16];
    int t = threadIdx.x;                      // 1024 threads
    int i = blockIdx.x * 1024 + t;
    unsigned v = (i < N) ? cnt[i] : 0u;
    #pragma unroll
    for (int d = 32; d; d >>= 1) v += __shfl_down(v, d);
    int wid = t >> 6, lane = t & 63;
    if (lane == 0) wsum[wid] = v;
    __syncthreads();
    if (t < 16) {
        unsigned w = wsum[t];
        #pragma unroll
        for (int d = 8; d; d >>= 1) w += __shfl_down(w, d, 16);
        if (t == 0) bsum[blockIdx.x] = w;
    }
}

__global__ void s2_k(const unsigned* bsum, unsigned* boff, int nb) {
    if (threadIdx.x == 0) {
        unsigned acc = 0;
        for (int i = 0; i < nb; ++i) { boff[i] = acc; acc += bsum[i]; }
        boff[nb] = acc;
    }
}

__global__ void s3_k(const unsigned* cnt, const unsigned* boff,
                     unsigned* offs, unsigned* cursor, int N) {
    __shared__ unsigned wsum[16];
    int t = threadIdx.x;
    int i = blockIdx.x * 1024 + t;
    unsigned v = (i < N) ? cnt[i] : 0u;
    int lane = t & 63, wid = t >> 6;
    unsigned s = v;
    #pragma unroll
    for (int d = 1; d < 64; d <<= 1) {
        unsigned u = __shfl_up(s, d);
        if (lane >= d) s += u;
    }
    if (lane == 63) wsum[wid] = s;
    __syncthreads();
    if (t < 16) {
        unsigned w = wsum[t];
        #pragma unroll
        for (int d = 1; d < 16; d <<= 1) {
            unsigned u = __shfl_up(w, d, 16);
            if (t >= d) w += u;
        }
        wsum[t] = w;
    }
    __syncthreads();
    unsigned wexcl = wid ? wsum[wid - 1] : 0u;
    unsigned excl = boff[blockIdx.x] + wexcl + (s - v);
    if (i < N) { offs[i] = excl; cursor[i] = excl; }
    if (i == N - 1) offs[N] = excl + v;
}

__global__ void scat_k(const void* ei, const float* ea, const unsigned* orw,
                       unsigned* cursor, unsigned long long* pay, int E) {
    const bool is64 = (*orw == 0u);
    const int* e32 = (const int*)ei;
    const long long* e64 = (const long long*)ei;
    int e = blockIdx.x * blockDim.x + threadIdx.x;
    int st = gridDim.x * blockDim.x;
    for (; e < E; e += st) {
        int r, c;
        if (is64) { r = (int)e64[e]; c = (int)e64[E + e]; }
        else      { r = e32[e];      c = e32[E + e]; }
        unsigned pos = atomicAdd(&cursor[c], 1u);
        pay[pos] = ((unsigned long long)__float_as_uint(ea[e]) << 32) | (unsigned)r;
    }
}

__global__ void deg2_k(const unsigned long long* pay, const unsigned* offs,
                       float* dis, int N) {
    int i = blockIdx.x * blockDim.x + threadIdx.x;
    if (i >= N) return;
    unsigned s = offs[i], e = offs[i + 1];
    float d = 1.0f;                            // self-loop weight
    for (unsigned j = s; j < e; ++j)
        d += __uint_as_float((unsigned)(pay[j] >> 32));
    dis[i] = (d > 0.f) ? rsqrtf(d) : 0.f;
}

__global__ void agg_k(const unsigned long long* pay, const unsigned* offs,
                      const float* dis, const float* x, float* agg, int N) {
    int t = blockIdx.x * blockDim.x + threadIdx.x;
    int g = t >> 3, l = t & 7;
    if (g >= N) return;
    unsigned s = offs[g], e = offs[g + 1];
    float acc = 0.f;
    for (unsigned j = s; j < e; ++j) {
        unsigned long long p = pay[j];
        int r = (int)(unsigned)p;
        float ew = __uint_as_float((unsigned)(p >> 32));
        acc += dis[r] * ew * x[(size_t)r * 8 + l];
    }
    float dc = dis[g];
    agg[(size_t)g * 8 + l] = dc * acc + dc * dc * x[(size_t)g * 8 + l];
}

__global__ void out_k(const float* Wm, const float* bv, const float* agg,
                      float* out, int N) {
    int lane = threadIdx.x & 63;
    int wid = blockIdx.x * (blockDim.x >> 6) + (threadIdx.x >> 6);
    int nw = gridDim.x * (blockDim.x >> 6);
    float wreg[8];
    #pragma unroll
    for (int k = 0; k < 8; ++k) wreg[k] = Wm[k * 64 + lane];
    float bj = bv[lane];
    for (int i = wid; i < N; i += nw) {
        float ink = (lane < 8) ? agg[(size_t)i * 8 + lane] : 0.f;
        float acc = bj;
        #pragma unroll
        for (int k = 0; k < 8; ++k)
            acc += __shfl(ink, k) * wreg[k];
        out[(size_t)i * 64 + lane] = acc;
    }
}

// ---------------- fallback (round-1 atomic path) ----------------
__global__ void fb_init_k(float* deg, float4* agg4, int N) {
    int i = blockIdx.x * blockDim.x + threadIdx.x;
    int st = gridDim.x * blockDim.x;
    for (; i < N; i += st) {
        deg[i] = 1.0f;
        agg4[2 * i] = make_float4(0.f, 0.f, 0.f, 0.f);
        agg4[2 * i + 1] = make_float4(0.f, 0.f, 0.f, 0.f);
    }
}
__global__ void fb_deg_k(const void* ei, const float* ea, const unsigned* orw,
                         float* deg, int E) {
    const bool is64 = (*orw == 0u);
    const int* e32 = (const int*)ei;
    const long long* e64 = (const long long*)ei;
    int e = blockIdx.x * blockDim.x + threadIdx.x;
    int st = gridDim.x * blockDim.x;
    for (; e < E; e += st) {
        int c = is64 ? (int)e64[E + e] : e32[E + e];
        atomicAdd(&deg[c], ea[e]);
    }
}
__global__ void fb_dis_k(float* deg, int N) {
    int i = blockIdx.x * blockDim.x + threadIdx.x;
    int st = gridDim.x * blockDim.x;
    for (; i < N; i += st) {
        float d = deg[i];
        deg[i] = (d > 0.f) ? rsqrtf(d) : 0.f;
    }
}
__global__ void fb_edge_k(const void* ei, const float* ea, const unsigned* orw,
                          const float* dis, const float* x, float* agg, int E) {
    const bool is64 = (*orw == 0u);
    const int* e32 = (const int*)ei;
    const long long* e64 = (const long long*)ei;
    int e = blockIdx.x * blockDim.x + threadIdx.x;
    int st = gridDim.x * blockDim.x;
    for (; e < E; e += st) {
        int r, c;
        if (is64) { r = (int)e64[e]; c = (int)e64[E + e]; }
        else      { r = e32[e];      c = e32[E + e]; }
        float nrm = dis[r] * ea[e] * dis[c];
        const float4* xr = (const float4*)(x + (size_t)r * 8);
        float4 a = xr[0];
        float4 b = xr[1];
        float* ag = agg + (size_t)c * 8;
        atomicAdd(ag + 0, nrm * a.x); atomicAdd(ag + 1, nrm * a.y);
        atomicAdd(ag + 2, nrm * a.z); atomicAdd(ag + 3, nrm * a.w);
        atomicAdd(ag + 4, nrm * b.x); atomicAdd(ag + 5, nrm * b.y);
        atomicAdd(ag + 6, nrm * b.z); atomicAdd(ag + 7, nrm * b.w);
    }
}
__global__ void fb_self_k(const float* dis, const float* x, float* agg, int N) {
    int t = blockIdx.x * blockDim.x + threadIdx.x;
    int st = gridDim.x * blockDim.x;
    for (; t < N * 8; t += st) {
        int i = t >> 3;
        float d = dis[i];
        agg[t] += d * d * x[t];
    }
}

extern "C" void kernel_launch(void* const* d_in, const int* in_sizes, int n_in,
                              void* d_out, int out_size, void* d_ws, size_t ws_size,
                              hipStream_t stream) {
    const float* x  = (const float*)d_in[0];
    const void*  ei = d_in[1];
    const float* ea = (const float*)d_in[2];
    const float* Wm = (const float*)d_in[3];
    const float* bv = (const float*)d_in[4];
    float* out = (float*)d_out;

    const int N = in_sizes[0] / 8;
    const int E = in_sizes[2];
    const int nb = (N + 1023) / 1024;

    char* ws = (char*)d_ws;
    size_t o = 0;
    unsigned* orw = (unsigned*)(ws + o);            o += 256;
    float* dis = (float*)(ws + o);                  o += ws_align((size_t)N * 4);
    unsigned* cnt = (unsigned*)(ws + o);            o += ws_align((size_t)N * 4);
    unsigned* offs = (unsigned*)(ws + o);           o += ws_align((size_t)(N + 1) * 4);
    unsigned* cursor = (unsigned*)(ws + o);         o += ws_align((size_t)N * 4);
    unsigned* bsum = (unsigned*)(ws + o);           o += ws_align((size_t)nb * 4);
    unsigned* boff = (unsigned*)(ws + o);           o += ws_align((size_t)(nb + 1) * 4);
    float* agg = (float*)(ws + o);                  o += ws_align((size_t)N * 8 * 4);
    unsigned long long* pay = (unsigned long long*)(ws + o);
    o += ws_align((size_t)E * 8);

    detect_k<<<1, 256, 0, stream>>>((const unsigned*)ei, orw);

    if (o <= ws_size) {
        zero_k<<<392, 256, 0, stream>>>(cnt, N);
        hist_k<<<2048, 256, 0, stream>>>(ei, orw, cnt, E);
        s1_k<<<nb, 1024, 0, stream>>>(cnt, bsum, N);
        s2_k<<<1, 64, 0, stream>>>(bsum, boff, nb);
        s3_k<<<nb, 1024, 0, stream>>>(cnt, boff, offs, cursor, N);
        scat_k<<<2048, 256, 0, stream>>>(ei, ea, orw, cursor, pay, E);
        deg2_k<<<(N + 255) / 256, 256, 0, stream>>>(pay, offs, dis, N);
        agg_k<<<(N * 8 + 255) / 256, 256, 0, stream>>>(pay, offs, dis, x, agg, N);
        out_k<<<2048, 256, 0, stream>>>(Wm, bv, agg, out, N);
    } else {
        // fallback: round-1 atomic path (needs only ~3.7 MB of ws)
        fb_init_k<<<(N + 255) / 256, 256, 0, stream>>>(dis, (float4*)agg, N);
        fb_deg_k<<<2048, 256, 0, stream>>>(ei, ea, orw, dis, E);
        fb_dis_k<<<(N + 255) / 256, 256, 0, stream>>>(dis, N);
        fb_edge_k<<<2048, 256, 0, stream>>>(ei, ea, orw, dis, x, agg, E);
        fb_self_k<<<2048, 256, 0, stream>>>(dis, x, agg, N);
        out_k<<<2048, 256, 0, stream>>>(Wm, bv, agg, out, N);
    }
}